// Round 3
// baseline (1539.957 us; speedup 1.0000x reference)
//
#include <hip/hip_runtime.h>

// ---------------------------------------------------------------------------
// Qwen2 attention forward: QKV proj + RoPE + causal GQA attention + O proj
// B=2 S=2048 HIDDEN=3584 NH=28 NKV=4 D=128
// ---------------------------------------------------------------------------

typedef __bf16 bf16x8 __attribute__((ext_vector_type(8)));
typedef float floatx4 __attribute__((ext_vector_type(4)));
typedef unsigned short ushort8v __attribute__((ext_vector_type(8)));
typedef unsigned short ushort4v __attribute__((ext_vector_type(4)));

__device__ __forceinline__ unsigned short f2bf(float f) {
    union { float f; unsigned int u; } v; v.f = f;
    return (unsigned short)((v.u + 0x7fffu + ((v.u >> 16) & 1u)) >> 16);
}
__device__ __forceinline__ float bf2f(unsigned short b) {
    union { unsigned int u; float f; } v; v.u = ((unsigned int)b) << 16;
    return v.f;
}
__device__ __forceinline__ floatx4 mfma16(bf16x8 a, bf16x8 b, floatx4 c) {
    return __builtin_amdgcn_mfma_f32_16x16x32_bf16(a, b, c, 0, 0, 0);
}
__device__ __forceinline__ bf16x8 ld8(const unsigned short* p) {
    ushort8v t = *(const ushort8v*)p;
    return __builtin_bit_cast(bf16x8, t);
}

// async global->LDS, 16B per lane; LDS dest = wave-uniform base + lane*16
#define GLL16(g, l) __builtin_amdgcn_global_load_lds( \
    (const __attribute__((address_space(1))) void*)(g), \
    (__attribute__((address_space(3))) void*)(l), 16, 0, 0)

// ---------------------------------------------------------------------------
// fp32 -> bf16 bulk convert of 5 arrays (vec4 granularity)
// ---------------------------------------------------------------------------
__global__ __launch_bounds__(256) void convert5(
    const float* __restrict__ s0, const float* __restrict__ s1,
    const float* __restrict__ s2, const float* __restrict__ s3,
    const float* __restrict__ s4,
    unsigned short* __restrict__ d0, unsigned short* __restrict__ d1,
    unsigned short* __restrict__ d2, unsigned short* __restrict__ d3,
    unsigned short* __restrict__ d4,
    int n0, int n1, int n2, int n3, int n4)
{
    int total = n0 + n1 + n2 + n3 + n4;
    for (int i = blockIdx.x * blockDim.x + threadIdx.x; i < total;
         i += gridDim.x * blockDim.x) {
        const float* s; unsigned short* d; int j = i;
        if (j < n0)      { s = s0; d = d0; }
        else { j -= n0; if (j < n1) { s = s1; d = d1; }
        else { j -= n1; if (j < n2) { s = s2; d = d2; }
        else { j -= n2; if (j < n3) { s = s3; d = d3; }
        else { j -= n3;   s = s4; d = d4; } } } }
        float4 v = ((const float4*)s)[j];
        ushort4v o;
        o[0] = f2bf(v.x); o[1] = f2bf(v.y); o[2] = f2bf(v.z); o[3] = f2bf(v.w);
        ((ushort4v*)d)[j] = o;
    }
}

// ---------------------------------------------------------------------------
// all-bf16 NT GEMM: C[m][n] = sum_k A[m][k]*B[n][k] (+bias[n])
// 128x128 tile, BK=32, global_load_lds staging into XOR-swizzled LDS.
// ---------------------------------------------------------------------------
template<bool HAS_BIAS, bool OUT_BF16>
__global__ __launch_bounds__(256) void gemm_bb(
    const unsigned short* __restrict__ A, const unsigned short* __restrict__ B,
    const float* __restrict__ bias, void* __restrict__ C,
    int K, int ldc)
{
    __shared__ unsigned short As[128 * 32];   // row stride 32 ushorts, swizzled
    __shared__ unsigned short Bs[128 * 32];

    const int tid = threadIdx.x, lane = tid & 63, w = tid >> 6;
    const int quad = lane >> 4, l16 = lane & 15;
    const int m0 = blockIdx.x * 128, n0 = blockIdx.y * 128;
    const int wm = (w & 1) * 64, wn = (w >> 1) * 64;

    floatx4 acc[4][4] = {};

    for (int k0 = 0; k0 < K; k0 += 32) {
        __syncthreads();
        #pragma unroll
        for (int p = 0; p < 2; ++p) {
            int c = (w * 2 + p) * 64 + lane;      // chunk 0..511
            int row = c >> 2, sp = c & 3;
            int slog = sp ^ ((row ^ (row >> 2)) & 3);
            GLL16(A + (size_t)(m0 + row) * K + k0 + slog * 8,
                  (unsigned short*)As + (w * 2 + p) * 512);
            GLL16(B + (size_t)(n0 + row) * K + k0 + slog * 8,
                  (unsigned short*)Bs + (w * 2 + p) * 512);
        }
        __syncthreads();
        bf16x8 af[4], bf[4];
        #pragma unroll
        for (int i = 0; i < 4; ++i) {
            int row = wm + i * 16 + l16;
            int sp = quad ^ ((row ^ (row >> 2)) & 3);
            af[i] = ld8((unsigned short*)As + row * 32 + sp * 8);
        }
        #pragma unroll
        for (int j = 0; j < 4; ++j) {
            int row = wn + j * 16 + l16;
            int sp = quad ^ ((row ^ (row >> 2)) & 3);
            bf[j] = ld8((unsigned short*)Bs + row * 32 + sp * 8);
        }
        #pragma unroll
        for (int i = 0; i < 4; ++i)
            #pragma unroll
            for (int j = 0; j < 4; ++j)
                acc[i][j] = mfma16(af[i], bf[j], acc[i][j]);
    }

    #pragma unroll
    for (int j = 0; j < 4; ++j) {
        int col = n0 + wn + j * 16 + l16;
        float bb = HAS_BIAS ? bias[col] : 0.0f;
        #pragma unroll
        for (int i = 0; i < 4; ++i) {
            int row = m0 + wm + i * 16 + quad * 4;
            #pragma unroll
            for (int r = 0; r < 4; ++r) {
                float v = acc[i][j][r] + bb;
                if (OUT_BF16)
                    ((unsigned short*)C)[(size_t)(row + r) * ldc + col] = f2bf(v);
                else
                    ((float*)C)[(size_t)(row + r) * ldc + col] = v;
            }
        }
    }
}

// ---------------------------------------------------------------------------
// v1 fp32-staging GEMM (fallback path when workspace is small)
// ---------------------------------------------------------------------------
template<bool A_BF16, bool HAS_BIAS, bool OUT_BF16>
__global__ __launch_bounds__(256) void gemm_nt(
    const void* __restrict__ Ap, const float* __restrict__ Bp,
    const float* __restrict__ bias, void* __restrict__ Cp,
    int K, int ldc)
{
    __shared__ unsigned short As[128][40];
    __shared__ unsigned short Bs[128][40];

    const int tid = threadIdx.x, lane = tid & 63, w = tid >> 6;
    const int quad = lane >> 4, l16 = lane & 15;
    const int m0 = blockIdx.x * 128, n0 = blockIdx.y * 128;
    const int wm = (w & 1) * 64, wn = (w >> 1) * 64;

    floatx4 acc[4][4] = {};

    for (int k0 = 0; k0 < K; k0 += 32) {
        __syncthreads();
        if (A_BF16) {
            const unsigned short* Ab = (const unsigned short*)Ap;
            #pragma unroll
            for (int p = 0; p < 2; ++p) {
                int idx = tid + p * 256;
                int row = idx >> 2, seg = idx & 3;
                ushort8v v = *(const ushort8v*)(Ab + (size_t)(m0 + row) * K + k0 + seg * 8);
                *(ushort8v*)&As[row][seg * 8] = v;
            }
        } else {
            const float* Af = (const float*)Ap;
            #pragma unroll
            for (int p = 0; p < 4; ++p) {
                int idx = tid + p * 256;
                int row = idx >> 3, seg = idx & 7;
                const float4 v = *(const float4*)(Af + (size_t)(m0 + row) * K + k0 + seg * 4);
                ushort4v b;
                b[0] = f2bf(v.x); b[1] = f2bf(v.y); b[2] = f2bf(v.z); b[3] = f2bf(v.w);
                *(ushort4v*)&As[row][seg * 4] = b;
            }
        }
        #pragma unroll
        for (int p = 0; p < 4; ++p) {
            int idx = tid + p * 256;
            int row = idx >> 3, seg = idx & 7;
            const float4 v = *(const float4*)(Bp + (size_t)(n0 + row) * K + k0 + seg * 4);
            ushort4v b;
            b[0] = f2bf(v.x); b[1] = f2bf(v.y); b[2] = f2bf(v.z); b[3] = f2bf(v.w);
            *(ushort4v*)&Bs[row][seg * 4] = b;
        }
        __syncthreads();
        bf16x8 af[4], bv[4];
        #pragma unroll
        for (int i = 0; i < 4; ++i) af[i] = ld8(&As[wm + i * 16 + l16][quad * 8]);
        #pragma unroll
        for (int j = 0; j < 4; ++j) bv[j] = ld8(&Bs[wn + j * 16 + l16][quad * 8]);
        #pragma unroll
        for (int i = 0; i < 4; ++i)
            #pragma unroll
            for (int j = 0; j < 4; ++j)
                acc[i][j] = mfma16(af[i], bv[j], acc[i][j]);
    }

    #pragma unroll
    for (int j = 0; j < 4; ++j) {
        int col = n0 + wn + j * 16 + l16;
        float bb = HAS_BIAS ? bias[col] : 0.0f;
        #pragma unroll
        for (int i = 0; i < 4; ++i) {
            int row = m0 + wm + i * 16 + quad * 4;
            #pragma unroll
            for (int r = 0; r < 4; ++r) {
                float v = acc[i][j][r] + bb;
                if (OUT_BF16)
                    ((unsigned short*)Cp)[(size_t)(row + r) * ldc + col] = f2bf(v);
                else
                    ((float*)Cp)[(size_t)(row + r) * ldc + col] = v;
            }
        }
    }
}

// ---------------------------------------------------------------------------
// RoPE in place: one block per token, 32 head-slices (28 q + 4 k)
// ---------------------------------------------------------------------------
__global__ __launch_bounds__(256) void rope2(
    unsigned short* __restrict__ Q, unsigned short* __restrict__ K,
    const float* __restrict__ cosp, const float* __restrict__ sinp)
{
    const int tok = blockIdx.x, tid = threadIdx.x;
    __shared__ float cs[128], ss[128];
    if (tid < 128) {
        cs[tid] = cosp[(size_t)tok * 128 + tid];
        ss[tid] = sinp[(size_t)tok * 128 + tid];
    }
    __syncthreads();

    ushort8v x[2], x2[2];
    unsigned short* bases[2];
    int segs[2];
    #pragma unroll
    for (int p = 0; p < 2; ++p) {
        int chunk = tid + p * 256;              // 0..511
        int hh = chunk >> 4, seg = chunk & 15;
        unsigned short* base = (hh < 28)
            ? Q + (size_t)tok * 3584 + hh * 128
            : K + (size_t)tok * 512 + (hh - 28) * 128;
        bases[p] = base; segs[p] = seg;
        x[p]  = *(const ushort8v*)(base + seg * 8);
        x2[p] = *(const ushort8v*)(base + (seg ^ 8) * 8);
    }
    __syncthreads();   // all reads complete before any thread writes
    #pragma unroll
    for (int p = 0; p < 2; ++p) {
        int seg = segs[p];
        ushort8v y;
        #pragma unroll
        for (int j = 0; j < 8; ++j) {
            int d = seg * 8 + j;
            float xv = bf2f(x[p][j]);
            float rv = bf2f(x2[p][j]);
            float rot = (seg < 8) ? -rv : rv;
            y[j] = f2bf(xv * cs[d] + rot * ss[d]);
        }
        *(ushort8v*)(bases[p] + seg * 8) = y;
    }
}

// ---------------------------------------------------------------------------
// V transpose: vb[4096 tok][512 gd] -> vt[512 gd][4096 tok]
// ---------------------------------------------------------------------------
__global__ __launch_bounds__(256) void transpose_v(
    const unsigned short* __restrict__ vb, unsigned short* __restrict__ vt)
{
    __shared__ unsigned short Ts[64][68];
    const int t0 = blockIdx.x * 64, c0 = blockIdx.y * 64;
    const int tid = threadIdx.x;
    #pragma unroll
    for (int it = 0; it < 4; ++it) {
        int idx = tid + it * 256;
        int row = idx >> 4, seg = idx & 15;
        *(ushort4v*)&Ts[row][seg * 4] =
            *(const ushort4v*)(vb + (size_t)(t0 + row) * 512 + c0 + seg * 4);
    }
    __syncthreads();
    #pragma unroll
    for (int it = 0; it < 4; ++it) {
        int idx = tid + it * 256;
        int gd = idx >> 4, seg = idx & 15;
        ushort4v y;
        #pragma unroll
        for (int j = 0; j < 4; ++j) y[j] = Ts[seg * 4 + j][gd];
        *(ushort4v*)(vt + (size_t)(c0 + gd) * 4096 + t0 + seg * 4) = y;
    }
}

// ---------------------------------------------------------------------------
// Flash attention v3: barrier-free. S^T = K Q^T so softmax rows live per-lane
// (q = lane&15): row reduce = 15 in-reg ops + 2 butterflies. K and V^T frags
// read directly from global (L2-hot). LDS only for per-wave P transpose.
// ---------------------------------------------------------------------------
__global__ __launch_bounds__(256) void attn3(
    const unsigned short* __restrict__ Q, const unsigned short* __restrict__ Kb,
    const unsigned short* __restrict__ Vt, unsigned short* __restrict__ O)
{
    const int qt = 31 - blockIdx.x;   // LPT: biggest blocks first
    const int h  = blockIdx.y;
    const int b  = blockIdx.z;
    const int kvh = h / 7;
    const int tid = threadIdx.x, lane = tid & 63, w = tid >> 6;
    const int quad = lane >> 4, l16 = lane & 15;

    __shared__ unsigned short Ps[4][16][80];   // per-wave P buffer (row=q, col=key)

    const float kScale = 0.08838834764831845f;  // 1/sqrt(128)

    // Q B-frags in registers: B[n=q(l16)][k=d(quad*8+j)+ks*32]
    bf16x8 bq[4];
    {
        const unsigned short* qp =
            Q + (size_t)(b * 2048 + qt * 64 + w * 16 + l16) * 3584 + h * 128 + quad * 8;
        #pragma unroll
        for (int ks = 0; ks < 4; ++ks) bq[ks] = ld8(qp + ks * 32);
    }

    const unsigned short* kbase = Kb + (size_t)(b * 2048) * 512 + kvh * 128;
    const unsigned short* vbase = Vt + (size_t)kvh * 128 * 4096 + b * 2048;

    floatx4 o[8] = {};                 // O[q=quad*4+r][d=d4*16+l16]
    float mrun = -1e30f, lrun = 0.f;   // softmax state for q-row = l16

    for (int kt = 0; kt <= qt; ++kt) {
        // ---- S^T = K Q^T : rows=keys, cols=q. A-frag = K from global ----
        floatx4 s[4] = {};             // s[i]: keys i*16 + quad*4 + r, q = l16
        const unsigned short* kp = kbase + (size_t)(kt * 64) * 512 + quad * 8;
        #pragma unroll
        for (int ks = 0; ks < 4; ++ks) {
            bf16x8 kf[4];
            #pragma unroll
            for (int i = 0; i < 4; ++i)
                kf[i] = ld8(kp + (size_t)(i * 16 + l16) * 512 + ks * 32);
            #pragma unroll
            for (int i = 0; i < 4; ++i)
                s[i] = mfma16(kf[i], bq[ks], s[i]);
        }

        // ---- causal mask (diag tile only) ----
        if (kt == qt) {
            int qg = qt * 64 + w * 16 + l16;
            #pragma unroll
            for (int i = 0; i < 4; ++i)
                #pragma unroll
                for (int r = 0; r < 4; ++r)
                    if (kt * 64 + i * 16 + quad * 4 + r > qg) s[i][r] = -1e30f;
        }

        // ---- online softmax: all 16 vals belong to q=l16 ----
        float mx = s[0][0];
        #pragma unroll
        for (int i = 0; i < 4; ++i)
            #pragma unroll
            for (int r = 0; r < 4; ++r) mx = fmaxf(mx, s[i][r]);
        mx = fmaxf(mx, __shfl_xor(mx, 16, 64));
        mx = fmaxf(mx, __shfl_xor(mx, 32, 64));
        float mnew  = fmaxf(mrun, mx);
        float alpha = __expf((mrun - mnew) * kScale);
        float p[4][4], rs = 0.f;
        #pragma unroll
        for (int i = 0; i < 4; ++i)
            #pragma unroll
            for (int r = 0; r < 4; ++r) {
                p[i][r] = __expf((s[i][r] - mnew) * kScale);
                rs += p[i][r];
            }
        rs += __shfl_xor(rs, 16, 64);
        rs += __shfl_xor(rs, 32, 64);
        lrun = lrun * alpha + rs;
        mrun = mnew;

        // ---- P -> per-wave LDS: row q=l16, keys i*16+quad*4+{0..3} ----
        #pragma unroll
        for (int i = 0; i < 4; ++i) {
            ushort4v pk;
            #pragma unroll
            for (int r = 0; r < 4; ++r) pk[r] = f2bf(p[i][r]);
            *(ushort4v*)&Ps[w][l16][i * 16 + quad * 4] = pk;
        }

        // ---- rescale O by alpha of its own q-row (quad*4+r) ----
        float al[4];
        #pragma unroll
        for (int r = 0; r < 4; ++r) al[r] = __shfl(alpha, quad * 20 + r, 64);
        #pragma unroll
        for (int d4 = 0; d4 < 8; ++d4)
            #pragma unroll
            for (int r = 0; r < 4; ++r) o[d4][r] *= al[r];

        // ---- O += P V : A-frag = P from LDS, B-frag = V^T from global ----
        #pragma unroll
        for (int ks2 = 0; ks2 < 2; ++ks2) {
            bf16x8 ap = ld8(&Ps[w][l16][ks2 * 32 + quad * 8]);
            const unsigned short* vp =
                vbase + (size_t)l16 * 4096 + kt * 64 + ks2 * 32 + quad * 8;
            #pragma unroll
            for (int d4 = 0; d4 < 8; ++d4) {
                bf16x8 bv = ld8(vp + (size_t)(d4 * 16) * 4096);
                o[d4] = mfma16(ap, bv, o[d4]);
            }
        }
    }

    // ---- epilogue: O /= l (l fetched from owner lane), write bf16 ----
    float lr[4];
    #pragma unroll
    for (int r = 0; r < 4; ++r) lr[r] = __shfl(lrun, quad * 20 + r, 64);
    #pragma unroll
    for (int d4 = 0; d4 < 8; ++d4) {
        int col = h * 128 + d4 * 16 + l16;
        #pragma unroll
        for (int r = 0; r < 4; ++r) {
            int row = b * 2048 + qt * 64 + w * 16 + quad * 4 + r;
            O[(size_t)row * 3584 + col] = f2bf(o[d4][r] / lr[r]);
        }
    }
}

// ---------------------------------------------------------------------------
extern "C" void kernel_launch(void* const* d_in, const int* in_sizes, int n_in,
                              void* d_out, int out_size, void* d_ws, size_t ws_size,
                              hipStream_t stream)
{
    (void)in_sizes; (void)n_in; (void)out_size;
    const float* hs   = (const float*)d_in[0];
    const float* cosp = (const float*)d_in[1];
    const float* sinp = (const float*)d_in[2];
    const float* Wq   = (const float*)d_in[3];
    const float* bq   = (const float*)d_in[4];
    const float* Wk   = (const float*)d_in[5];
    const float* bk   = (const float*)d_in[6];
    const float* Wv   = (const float*)d_in[7];
    const float* bv   = (const float*)d_in[8];
    const float* Wo   = (const float*)d_in[9];
    float* out = (float*)d_out;

    const size_t NHS = 14680064;   // 4096*3584
    const size_t NWQ = 12845056;   // 3584*3584
    const size_t NWKV = 1835008;   // 512*3584
    const size_t NWO = 12845056;
    const size_t NQ  = 14680064;
    const size_t NKV = 2097152;    // 4096*512

    const size_t need = 2 * (NHS + NQ + NQ + 3 * NKV + NWQ + 2 * NWKV + NWO);
    dim3 blk(256);

    if (ws_size >= need) {
        unsigned short* hb  = (unsigned short*)d_ws;
        unsigned short* qb  = hb + NHS;
        unsigned short* ab  = qb + NQ;
        unsigned short* kb  = ab + NQ;
        unsigned short* vb  = kb + NKV;
        unsigned short* vt  = vb + NKV;
        unsigned short* Wqb = vt + NKV;
        unsigned short* Wkb = Wqb + NWQ;
        unsigned short* Wvb = Wkb + NWKV;
        unsigned short* Wob = Wvb + NWKV;

        convert5<<<dim3(1024), blk, 0, stream>>>(
            hs, Wq, Wk, Wv, Wo, hb, Wqb, Wkb, Wvb, Wob,
            (int)(NHS / 4), (int)(NWQ / 4), (int)(NWKV / 4), (int)(NWKV / 4), (int)(NWO / 4));

        gemm_bb<true, true><<<dim3(32, 28), blk, 0, stream>>>(hb, Wqb, bq, qb, 3584, 3584);
        gemm_bb<true, true><<<dim3(32, 4),  blk, 0, stream>>>(hb, Wkb, bk, kb, 3584, 512);
        gemm_bb<true, true><<<dim3(32, 4),  blk, 0, stream>>>(hb, Wvb, bv, vb, 3584, 512);
        rope2<<<dim3(4096), blk, 0, stream>>>(qb, kb, cosp, sinp);
        transpose_v<<<dim3(64, 8), blk, 0, stream>>>(vb, vt);
        attn3<<<dim3(32, 28, 2), blk, 0, stream>>>(qb, kb, vt, ab);
        gemm_bb<false, false><<<dim3(32, 28), blk, 0, stream>>>(ab, Wob, nullptr, out, 3584, 3584);
    } else {
        unsigned short* qb = (unsigned short*)d_ws;
        unsigned short* kb = qb + NQ;
        unsigned short* vb = kb + NKV;
        unsigned short* vt = vb + NKV;
        unsigned short* ab = vt + NKV;

        gemm_nt<false, true, true><<<dim3(32, 28), blk, 0, stream>>>(hs, Wq, bq, qb, 3584, 3584);
        gemm_nt<false, true, true><<<dim3(32, 4),  blk, 0, stream>>>(hs, Wk, bk, kb, 3584, 512);
        gemm_nt<false, true, true><<<dim3(32, 4),  blk, 0, stream>>>(hs, Wv, bv, vb, 3584, 512);
        rope2<<<dim3(4096), blk, 0, stream>>>(qb, kb, cosp, sinp);
        transpose_v<<<dim3(64, 8), blk, 0, stream>>>(vb, vt);
        attn3<<<dim3(32, 28, 2), blk, 0, stream>>>(qb, kb, vt, ab);
        gemm_nt<true, false, false><<<dim3(32, 28), blk, 0, stream>>>(ab, Wo, nullptr, out, 3584, 3584);
    }
}